// Round 10
// baseline (105.045 us; speedup 1.0000x reference)
//
#include <hip/hip_runtime.h>

typedef _Float16 f16;
typedef _Float16 f16x8 __attribute__((ext_vector_type(8)));
typedef float f32x4 __attribute__((ext_vector_type(4)));
typedef unsigned int u32;
typedef const __attribute__((address_space(1))) u32* gas1_t;
typedef __attribute__((address_space(3))) u32* las3_t;

#define WGRAN 460800   // 225 * 2048 granules of 8 halves (W)
#define IGRAN 32768    // 262144/8 granules (inp)

// fp32 -> f16 with W permuted into the fragment-ready layout:
// W_h[dxdy][i][o][quad] (granules of 8 halves) = W[dxdy][o][i][quad*8+u]
__global__ __launch_bounds__(256) void convert_kernel(
    const float* __restrict__ W, const float* __restrict__ inp,
    f16* __restrict__ W_h, f16* __restrict__ inp_h)
{
    const int g = blockIdx.x * 256 + threadIdx.x;   // grid sized exactly
    if (g < WGRAN) {
        const int dxdy = g >> 11;
        const int r = g & 2047;
        const int i = r >> 6, o = (r >> 2) & 15, quad = r & 3;
        const float* src = W + (size_t)dxdy * 16384 + o * 1024 + i * 32 + quad * 8;
        const float4 v0 = *(const float4*)src;
        const float4 v1 = *(const float4*)(src + 4);
        f16x8 h = { (f16)v0.x, (f16)v0.y, (f16)v0.z, (f16)v0.w,
                    (f16)v1.x, (f16)v1.y, (f16)v1.z, (f16)v1.w };
        *(f16x8*)(W_h + (size_t)g * 8) = h;
    } else {
        const int k = g - WGRAN;
        const float* src = inp + (size_t)k * 8;
        const float4 v0 = *(const float4*)src;
        const float4 v1 = *(const float4*)(src + 4);
        f16x8 h = { (f16)v0.x, (f16)v0.y, (f16)v0.z, (f16)v0.w,
                    (f16)v1.x, (f16)v1.y, (f16)v1.z, (f16)v1.w };
        *(f16x8*)(inp_h + (size_t)k * 8) = h;
    }
}

// R10: R4 structure + COUNTED-vmcnt BARRIERS (T4).
// R9 falsified write-amp; the remaining per-Y stall is __syncthreads()'s
// implicit s_waitcnt vmcnt(0): it drains the epilogue's 8 global stores to
// cold out-lines every Y, though only the 8 tile-(Y+1) DMAs guard the LDS
// buffer swap. Per-thread VMEM order per Y = [8 DMA oldest, 8 stores
// newest], so s_waitcnt vmcnt(8) + raw s_barrier drains exactly the DMAs
// (plus Y-1's stores, which had a full K-loop to retire) and leaves this
// Y's stores in flight. sched_barrier(0) fences pin issue order (rule #18).
__global__ __launch_bounds__(256, 2) void rel_mfma7(
    const f16* __restrict__ W_h,    // [dxdy][i][o][quad][8]
    const f16* __restrict__ inp_h,  // (128,8,8,32) f16
    const float* __restrict__ bias, // (15,15,16)
    float* __restrict__ out)        // (128,8,8,8,8,16)
{
    extern __shared__ __align__(16) f16 Wl[];   // 2 x 32768 B

    const int hw = blockIdx.x;                  // 512 = (x,y,X), X fastest
    const int X = hw & 7, y = (hw >> 3) & 7, x = (hw >> 6) & 7;
    const int dx = X - x + 7;

    const int t = threadIdx.x;
    const int lane = t & 63;
    const int wave = t >> 6;       // 0..3 -> b-tiles 2w, 2w+1
    const int quad = lane >> 4;
    const int m = lane & 15;       // A-row (b%16) and B-col (o)

    // 8 tiles for Y=0..7 start at dxdy = dx*15 + (7-y), contiguous.
    const f16* wbase = W_h + (size_t)(dx * 15 + 7 - y) * 16384;

    // ---- stage tile Y=0 into buffer 0 ----
    #pragma unroll
    for (int it = 0; it < 8; ++it) {
        const int idx = (it * 256 + t) * 8;          // 16 B granule
        __builtin_amdgcn_global_load_lds((gas1_t)(wbase + idx),
                                         (las3_t)&Wl[idx], 16, 0, 0);
    }

    // ---- a-rows (Y-invariant) + all 8 c-frags into registers ----
    f16x8 a0[4], a1[4], c0[8], c1[8];
    const int b0 = wave * 32 + m;
    const int b1 = b0 + 16;
    {
        const f16* ar0 = inp_h + ((b0 * 8 + x) * 8 + y) * 32;
        const f16* ar1 = inp_h + ((b1 * 8 + x) * 8 + y) * 32;
        #pragma unroll
        for (int g = 0; g < 4; ++g) {
            a0[g] = *(const f16x8*)(ar0 + g * 8);
            a1[g] = *(const f16x8*)(ar1 + g * 8);
        }
        const f16* cr0 = inp_h + (b0 * 8 + X) * 256 + quad * 8;  // Y=0 row
        const f16* cr1 = inp_h + (b1 * 8 + X) * 256 + quad * 8;
        #pragma unroll
        for (int Yi = 0; Yi < 8; ++Yi) {
            c0[Yi] = *(const f16x8*)(cr0 + Yi * 32);
            c1[Yi] = *(const f16x8*)(cr1 + Yi * 32);
        }
    }

    __syncthreads();   // prologue: full drain (DMA + a/c loads), once

    const int bid_base = ((x * 8 + y) * 8 + X) * 8;   // bid = bid_base + Y

    #pragma unroll     // full unroll: keeps c0[Y]/c1[Y] statically indexed
    for (int Y = 0; Y < 8; ++Y) {
        const int cur = Y & 1;

        // ---- issue prefetch of tile Y+1 into the other buffer ----
        if (Y < 7) {
            const f16* nbase = wbase + (size_t)(Y + 1) * 16384;
            f16* ldst = Wl + (cur ^ 1) * 16384;
            #pragma unroll
            for (int it = 0; it < 8; ++it) {
                const int idx = (it * 256 + t) * 8;
                __builtin_amdgcn_global_load_lds((gas1_t)(nbase + idx),
                                                 (las3_t)&ldst[idx], 16, 0, 0);
            }
        }
        __builtin_amdgcn_sched_barrier(0);   // DMAs pinned before K-loop

        // ---- K-loop: 32 steps, 2-deep bfrag prefetch ----
        f32x4 acc0 = {0.f, 0.f, 0.f, 0.f};
        f32x4 acc1 = {0.f, 0.f, 0.f, 0.f};
        const f16* wl = Wl + cur * 16384 + m * 32 + quad * 8;
        f16x8 bfrag = *(const f16x8*)(wl);               // kb = 0
        #pragma unroll
        for (int kb = 0; kb < 32; ++kb) {
            const f16x8 bcur = bfrag;
            if (kb < 31)
                bfrag = *(const f16x8*)(wl + (kb + 1) * 512);
            const f16 av0 = a0[kb >> 3][kb & 7];
            const f16 av1 = a1[kb >> 3][kb & 7];
            const f16x8 af0 = c0[Y] * av0;   // P[b, kb*32 + quad*8 + r]
            const f16x8 af1 = c1[Y] * av1;
            acc0 = __builtin_amdgcn_mfma_f32_16x16x32_f16(af0, bcur, acc0, 0, 0, 0);
            acc1 = __builtin_amdgcn_mfma_f32_16x16x32_f16(af1, bcur, acc1, 0, 0, 0);
        }

        // ---- epilogue: fire-and-forget stores (not drained this Y) ----
        const int dxdy = dx * 15 + (Y - y + 7);
        const int bid = bid_base + Y;
        const float bv = bias[dxdy * 16 + m];
        #pragma unroll
        for (int r = 0; r < 4; ++r) {
            const int bb = wave * 32 + quad * 4 + r;
            out[((size_t)bb * 4096 + bid) * 16 + m]        = acc0[r] + bv;
            out[((size_t)(bb + 16) * 4096 + bid) * 16 + m] = acc1[r] + bv;
        }

        // ---- counted barrier: drain DMAs only, leave stores in flight ----
        if (Y < 7) {
            __builtin_amdgcn_sched_barrier(0);                 // stores pinned above
            asm volatile("s_waitcnt vmcnt(8)" ::: "memory");   // drains [old stores]+[8 DMA]
            __builtin_amdgcn_s_barrier();
            __builtin_amdgcn_sched_barrier(0);                 // no ds_read hoist
        }
    }
    // final Y's stores retire at end-of-kernel drain
}

extern "C" void kernel_launch(void* const* d_in, const int* in_sizes, int n_in,
                              void* d_out, int out_size, void* d_ws, size_t ws_size,
                              hipStream_t stream)
{
    const float* inp  = (const float*)d_in[0];  // (128,8,8,32)
    const float* W    = (const float*)d_in[1];  // (15,15,16,32,32)
    const float* bias = (const float*)d_in[2];  // (15,15,16)
    float* out = (float*)d_out;

    f16* W_h   = (f16*)d_ws;                         // 7,372,800 halves
    f16* inp_h = (f16*)d_ws + (size_t)WGRAN * 8;     //   262,144 halves

    hipLaunchKernelGGL(convert_kernel, dim3((WGRAN + IGRAN) / 256), dim3(256), 0,
                       stream, W, inp, W_h, inp_h);
    hipLaunchKernelGGL(rel_mfma7, dim3(512), dim3(256), 65536, stream,
                       W_h, inp_h, bias, out);
}

// Round 12
// 104.850 us; speedup vs baseline: 1.0019x; 1.0019x over previous
//
#include <hip/hip_runtime.h>

typedef _Float16 f16;
typedef _Float16 f16x8 __attribute__((ext_vector_type(8)));
typedef float f32x4 __attribute__((ext_vector_type(4)));
typedef unsigned int u32;
typedef const __attribute__((address_space(1))) u32* gas1_t;
typedef __attribute__((address_space(3))) u32* las3_t;

#define WGRAN 460800   // 225 * 2048 granules of 8 halves (W)
#define IGRAN 32768    // 262144/8 granules (inp)

// fp32 -> f16 with W permuted into the fragment-ready layout:
// W_h[dxdy][i][o][quad] (granules of 8 halves) = W[dxdy][o][i][quad*8+u]
__global__ __launch_bounds__(256) void convert_kernel(
    const float* __restrict__ W, const float* __restrict__ inp,
    f16* __restrict__ W_h, f16* __restrict__ inp_h)
{
    const int g = blockIdx.x * 256 + threadIdx.x;   // grid sized exactly
    if (g < WGRAN) {
        const int dxdy = g >> 11;
        const int r = g & 2047;
        const int i = r >> 6, o = (r >> 2) & 15, quad = r & 3;
        const float* src = W + (size_t)dxdy * 16384 + o * 1024 + i * 32 + quad * 8;
        const float4 v0 = *(const float4*)src;
        const float4 v1 = *(const float4*)(src + 4);
        f16x8 h = { (f16)v0.x, (f16)v0.y, (f16)v0.z, (f16)v0.w,
                    (f16)v1.x, (f16)v1.y, (f16)v1.z, (f16)v1.w };
        *(f16x8*)(W_h + (size_t)g * 8) = h;
    } else {
        const int k = g - WGRAN;
        const float* src = inp + (size_t)k * 8;
        const float4 v0 = *(const float4*)src;
        const float4 v1 = *(const float4*)(src + 4);
        f16x8 h = { (f16)v0.x, (f16)v0.y, (f16)v0.z, (f16)v0.w,
                    (f16)v1.x, (f16)v1.y, (f16)v1.z, (f16)v1.w };
        *(f16x8*)(inp_h + (size_t)k * 8) = h;
    }
}

// R12: T3 PHASE INTERLEAVE (the catalog's regime gate, finally satisfied).
// R10 applied T4 (counted vmcnt) on a 2-phase loop -- the T-catalog says
// that's null by construction (m218b/m230); T4/T5 pay only inside a
// per-phase barrier convoy (T3). This kernel splits each Y's K-loop into
// 4 phases x 8 kb: {issue 8 ds_read (+phase0: 8 staging DMAs)} -> s_barrier
// -> setprio(1) -> 16 MFMA -> setprio(0) -> s_barrier. Waves convoy so LDS
// bursts and MFMA clusters alternate; the 2 independent blocks/CU overlap
// read-phase vs MFMA-phase (m114). Buffer swap still guarded by the once-
// per-Y counted vmcnt(8) + barrier (R10-verified). Bias hoisted to bv[8].
__global__ __launch_bounds__(256, 2) void rel_mfma8(
    const f16* __restrict__ W_h,    // [dxdy][i][o][quad][8]
    const f16* __restrict__ inp_h,  // (128,8,8,32) f16
    const float* __restrict__ bias, // (15,15,16)
    float* __restrict__ out)        // (128,8,8,8,8,16)
{
    extern __shared__ __align__(16) f16 Wl[];   // 2 x 32768 B

    const int hw = blockIdx.x;                  // 512 = (x,y,X), X fastest
    const int X = hw & 7, y = (hw >> 3) & 7, x = (hw >> 6) & 7;
    const int dx = X - x + 7;

    const int t = threadIdx.x;
    const int lane = t & 63;
    const int wave = t >> 6;       // 0..3 -> b-tiles 2w, 2w+1
    const int quad = lane >> 4;
    const int m = lane & 15;       // A-row (b%16) and B-col (o)

    // 8 tiles for Y=0..7 start at dxdy = dx*15 + (7-y), contiguous.
    const f16* wbase = W_h + (size_t)(dx * 15 + 7 - y) * 16384;

    // ---- stage tile Y=0 into buffer 0 ----
    #pragma unroll
    for (int it = 0; it < 8; ++it) {
        const int idx = (it * 256 + t) * 8;          // 16 B granule
        __builtin_amdgcn_global_load_lds((gas1_t)(wbase + idx),
                                         (las3_t)&Wl[idx], 16, 0, 0);
    }

    // ---- a-rows (Y-invariant) + all 8 c-frags + bias into registers ----
    f16x8 a0[4], a1[4], c0[8], c1[8];
    float bv[8];
    const int b0 = wave * 32 + m;
    const int b1 = b0 + 16;
    {
        const f16* ar0 = inp_h + ((b0 * 8 + x) * 8 + y) * 32;
        const f16* ar1 = inp_h + ((b1 * 8 + x) * 8 + y) * 32;
        #pragma unroll
        for (int g = 0; g < 4; ++g) {
            a0[g] = *(const f16x8*)(ar0 + g * 8);
            a1[g] = *(const f16x8*)(ar1 + g * 8);
        }
        const f16* cr0 = inp_h + (b0 * 8 + X) * 256 + quad * 8;  // Y=0 row
        const f16* cr1 = inp_h + (b1 * 8 + X) * 256 + quad * 8;
        #pragma unroll
        for (int Yi = 0; Yi < 8; ++Yi) {
            c0[Yi] = *(const f16x8*)(cr0 + Yi * 32);
            c1[Yi] = *(const f16x8*)(cr1 + Yi * 32);
            bv[Yi] = bias[(dx * 15 + (Yi - y + 7)) * 16 + m];
        }
    }

    __syncthreads();   // prologue: full drain (DMA + loads), once

    const int bid_base = ((x * 8 + y) * 8 + X) * 8;   // bid = bid_base + Y

    #pragma unroll     // full unroll: all indexing static
    for (int Y = 0; Y < 8; ++Y) {
        const int cur = Y & 1;
        const f16* wl = Wl + cur * 16384 + m * 32 + quad * 8;

        f32x4 acc0 = {0.f, 0.f, 0.f, 0.f};
        f32x4 acc1 = {0.f, 0.f, 0.f, 0.f};

        // ---- 4 phases x 8 kb: read-burst -> barrier -> MFMA-cluster ----
        #pragma unroll
        for (int ph = 0; ph < 4; ++ph) {
            // issue this phase's 8 bfrag reads (burst)
            f16x8 bf[8];
            #pragma unroll
            for (int k = 0; k < 8; ++k)
                bf[k] = *(const f16x8*)(wl + (ph * 8 + k) * 512);

            // phase 0 also issues the 8 staging DMAs for tile Y+1
            if (ph == 0 && Y < 7) {
                const f16* nbase = wbase + (size_t)(Y + 1) * 16384;
                f16* ldst = Wl + (cur ^ 1) * 16384;
                #pragma unroll
                for (int it = 0; it < 8; ++it) {
                    const int idx = (it * 256 + t) * 8;
                    __builtin_amdgcn_global_load_lds((gas1_t)(nbase + idx),
                                                     (las3_t)&ldst[idx], 16, 0, 0);
                }
            }

            __builtin_amdgcn_s_barrier();      // convoy: reads issued by all
            __builtin_amdgcn_s_setprio(1);
            #pragma unroll
            for (int k = 0; k < 8; ++k) {
                const int kb = ph * 8 + k;
                const f16 av0 = a0[kb >> 3][kb & 7];
                const f16 av1 = a1[kb >> 3][kb & 7];
                const f16x8 af0 = c0[Y] * av0;   // P[b, kb*32 + quad*8 + r]
                const f16x8 af1 = c1[Y] * av1;
                acc0 = __builtin_amdgcn_mfma_f32_16x16x32_f16(af0, bf[k], acc0, 0, 0, 0);
                acc1 = __builtin_amdgcn_mfma_f32_16x16x32_f16(af1, bf[k], acc1, 0, 0, 0);
            }
            __builtin_amdgcn_s_setprio(0);
            __builtin_amdgcn_s_barrier();      // phase close
        }

        // ---- epilogue: fire-and-forget stores (not drained this Y) ----
        const int bid = bid_base + Y;
        #pragma unroll
        for (int r = 0; r < 4; ++r) {
            const int bb = wave * 32 + quad * 4 + r;
            out[((size_t)bb * 4096 + bid) * 16 + m]        = acc0[r] + bv[Y];
            out[((size_t)(bb + 16) * 4096 + bid) * 16 + m] = acc1[r] + bv[Y];
        }

        // ---- swap barrier: drain DMAs only, leave stores in flight ----
        if (Y < 7) {
            __builtin_amdgcn_sched_barrier(0);                 // stores pinned above
            asm volatile("s_waitcnt vmcnt(8)" ::: "memory");   // 8 newest = stores
            __builtin_amdgcn_s_barrier();
            __builtin_amdgcn_sched_barrier(0);                 // no read hoist
        }
    }
    // final Y's stores retire at end-of-kernel drain
}

extern "C" void kernel_launch(void* const* d_in, const int* in_sizes, int n_in,
                              void* d_out, int out_size, void* d_ws, size_t ws_size,
                              hipStream_t stream)
{
    const float* inp  = (const float*)d_in[0];  // (128,8,8,32)
    const float* W    = (const float*)d_in[1];  // (15,15,16,32,32)
    const float* bias = (const float*)d_in[2];  // (15,15,16)
    float* out = (float*)d_out;

    f16* W_h   = (f16*)d_ws;                         // 7,372,800 halves
    f16* inp_h = (f16*)d_ws + (size_t)WGRAN * 8;     //   262,144 halves

    hipLaunchKernelGGL(convert_kernel, dim3((WGRAN + IGRAN) / 256), dim3(256), 0,
                       stream, W, inp, W_h, inp_h);
    hipLaunchKernelGGL(rel_mfma8, dim3(512), dim3(256), 65536, stream,
                       W_h, inp_h, bias, out);
}